// Round 15
// baseline (347.730 us; speedup 1.0000x reference)
//
#include <hip/hip_runtime.h>
#include <cmath>

#define D  128   // D_EDGE
#define DR 64    // D_RBF
#define NB 32    // nodes per block in stage1

typedef float fx4    __attribute__((ext_vector_type(4)));
typedef short short8v __attribute__((ext_vector_type(8)));

__device__ __forceinline__ float ssp_f(float x) {
  // softplus(x) - log(2), numerically stable
  float m = fmaxf(x, 0.0f);
  float t = __expf(-fabsf(x));
  return m + __logf(1.0f + t) - 0.69314718055994531f;
}

__device__ __forceinline__ short f2bf(float f) {   // fp32 -> bf16 (RNE)
  unsigned u = __float_as_uint(f);
  u = (u + 0x7FFFu + ((u >> 16) & 1u)) >> 16;
  return (short)u;
}

// ---------------------------------------------------------------------------
// stage0: W_eff = W_cat[:, :128] @ W_rbf (128x64), b_eff; also bf16 copy.
// ---------------------------------------------------------------------------
__global__ __launch_bounds__(256) void stage0_kernel(
    const float* __restrict__ W_rbf, const float* __restrict__ b_rbf,
    const float* __restrict__ W_cat, const float* __restrict__ b_cat,
    float* __restrict__ weff, unsigned short* __restrict__ weffh,
    float* __restrict__ beff, int write_bf16)
{
  int gid = blockIdx.x * 256 + threadIdx.x;
  if (gid < D * DR) {
    int o = gid >> 6;
    int r = gid & 63;
    float acc = 0.0f;
    #pragma unroll 8
    for (int d = 0; d < D; ++d)
      acc = fmaf(W_cat[o * 384 + d], W_rbf[d * DR + r], acc);
    weff[gid] = acc;
    if (write_bf16) weffh[gid] = (unsigned short)f2bf(acc);
  }
  if (gid < D) {
    float acc = b_cat[gid];
    #pragma unroll 8
    for (int d = 0; d < D; ++d)
      acc = fmaf(b_rbf[d], W_cat[gid * 384 + d], acc);
    beff[gid] = acc;
  }
}

// ---------------------------------------------------------------------------
// stage1: Pj[n][o] = vi[n] . W_cat[o][128:256], Pi[n][o] = vi[n] . W_cat[o][256:384]
// ---------------------------------------------------------------------------
__global__ __launch_bounds__(256) void stage1_kernel(
    const float* __restrict__ vi, const float* __restrict__ W_cat,
    float* __restrict__ Pj, float* __restrict__ Pi, int N)
{
  __shared__ float vrow[NB * D];
  int base = blockIdx.x * NB;
  int t = threadIdx.x;
  for (int idx = t * 4; idx < NB * D; idx += 1024) {
    int n = base + (idx >> 7);
    float4 v = make_float4(0.f, 0.f, 0.f, 0.f);
    if (n < N) v = *(const float4*)&vi[(long)n * D + (idx & 127)];
    *(float4*)&vrow[idx] = v;
  }
  __syncthreads();

  int o     = t & 127;
  int which = t >> 7;
  const float* w = W_cat + (long)o * 384 + 128 + which * 128;
  float* P = which ? Pi : Pj;

  float acc[NB];
  #pragma unroll
  for (int n = 0; n < NB; ++n) acc[n] = 0.0f;

  for (int dd = 0; dd < D; dd += 4) {
    float4 wv = *(const float4*)&w[dd];
    #pragma unroll
    for (int n = 0; n < NB; ++n) {
      float4 v = *(const float4*)&vrow[n * D + dd];
      acc[n] = fmaf(wv.x, v.x, acc[n]);
      acc[n] = fmaf(wv.y, v.y, acc[n]);
      acc[n] = fmaf(wv.z, v.z, acc[n]);
      acc[n] = fmaf(wv.w, v.w, acc[n]);
    }
  }
  #pragma unroll
  for (int n = 0; n < NB; ++n) {
    int nn = base + n;
    if (nn < N) P[(long)nn * D + o] = acc[n];
  }
}

// ---------------------------------------------------------------------------
// MFMA edge kernel v5: 16x16x32 bf16, wave = 16 edges x 8 chan-steps of 16.
// Designed for <=64 VGPR (the 8-waves/SIMD occupancy tier; measured tiers
// are exactly 64/128/256 — R11..R14): A 8 + B 8 + acc 4 + gathers 8 +
// offsets 12 + temps. TLP (8 waves/SIMD) hides gather latency instead of
// in-register pipelining (which cost the 128 boundary in R12/R14).
// C/D layout (m89-verified): col=lane&15 (chan), row=(lane>>4)*4+reg (edge).
// A/B k-map: k = (lane>>4)*8 + i (+32 for frag1), same bijection for A and B
// => result correct regardless of HW's internal k ordering.
// All gather/store addresses: uniform base + precomputed 32-bit byte offset
// + imm ct*64 — zero per-ct address arithmetic.
// NOTE: never set min-waves launch bounds here (R3/R13: forced caps spill
// ~900MB to scratch).
// ---------------------------------------------------------------------------
__global__ __launch_bounds__(256) void edge_mfma_kernel(
    const float* __restrict__ rbf, const int* __restrict__ eidx,
    const unsigned short* __restrict__ weffh, const float* __restrict__ beff,
    const float* __restrict__ Pj, const float* __restrict__ Pi,
    float* __restrict__ out, int E)
{
  const int t    = threadIdx.x;
  const int lane = t & 63;
  const int n16  = lane & 15;   // chan within 16-step / A edge row
  const int kg   = lane >> 4;   // k-group (0..3) / C/D row-group
  const long wid = (long)blockIdx.x * 4 + (t >> 6);
  const long tb  = wid * 16;
  if (tb >= (long)E) return;

  // ---- A fragments: rbf row (tb+n16), k = kg*8..+8 (+32 for frag1) ----
  long ar = tb + n16; if (ar > (long)E - 1) ar = (long)E - 1;
  const float* arow = rbf + ar * DR + kg * 8;
  short8v A0, A1;
  {
    fx4 l0 = __builtin_nontemporal_load((const fx4*)&arow[0]);
    fx4 h0 = __builtin_nontemporal_load((const fx4*)&arow[4]);
    fx4 l1 = __builtin_nontemporal_load((const fx4*)&arow[32]);
    fx4 h1 = __builtin_nontemporal_load((const fx4*)&arow[36]);
    A0[0] = f2bf(l0.x); A0[1] = f2bf(l0.y); A0[2] = f2bf(l0.z); A0[3] = f2bf(l0.w);
    A0[4] = f2bf(h0.x); A0[5] = f2bf(h0.y); A0[6] = f2bf(h0.z); A0[7] = f2bf(h0.w);
    A1[0] = f2bf(l1.x); A1[1] = f2bf(l1.y); A1[2] = f2bf(l1.z); A1[3] = f2bf(l1.w);
    A1[4] = f2bf(h1.x); A1[5] = f2bf(h1.y); A1[6] = f2bf(h1.z); A1[7] = f2bf(h1.w);
  }

  // ---- per-reg byte offsets (C/D edge row m = kg*4 + reg) ----
  int joff[4], ioff[4], soff[4];
  bool ok[4];
  #pragma unroll
  for (int reg = 0; reg < 4; ++reg) {
    const long ge = tb + kg * 4 + reg;
    ok[reg] = ge < (long)E;
    const long gc = ok[reg] ? ge : (long)E - 1;
    joff[reg] = eidx[(long)E + gc] * 512 + n16 * 4;  // h_j -> Pj (bytes)
    ioff[reg] = eidx[gc] * 512 + n16 * 4;            // h_i -> Pi (bytes)
    soff[reg] = (int)(ge * 512) + n16 * 4;           // out (bytes), guarded
  }

  const char* PjB = (const char*)Pj;
  const char* PiB = (const char*)Pi;
  char* outB = (char*)out;

  #pragma unroll
  for (int ct = 0; ct < 8; ++ct) {
    // B fragments for this 16-chan step (L1-resident, 16 KB table)
    short8v B0 = *(const short8v*)&weffh[(ct * 16 + n16) * DR + kg * 8];
    short8v B1 = *(const short8v*)&weffh[(ct * 16 + n16) * DR + 32 + kg * 8];
    // gathers: imm-offset loads, 8 in flight
    float gj[4], gi[4];
    #pragma unroll
    for (int reg = 0; reg < 4; ++reg) {
      gj[reg] = *(const float*)(PjB + (long)joff[reg] + ct * 64);
      gi[reg] = *(const float*)(PiB + (long)ioff[reg] + ct * 64);
    }
    const float bias = beff[ct * 16 + n16];   // col-only -> same for all regs

    fx4 acc = {bias, bias, bias, bias};
    acc = __builtin_amdgcn_mfma_f32_16x16x32_bf16(A0, B0, acc, 0, 0, 0);
    acc = __builtin_amdgcn_mfma_f32_16x16x32_bf16(A1, B1, acc, 0, 0, 0);

    #pragma unroll
    for (int reg = 0; reg < 4; ++reg) {
      const float v = ssp_f(acc[reg] + gj[reg] + gi[reg]);
      if (ok[reg]) *(float*)(outB + (long)soff[reg] + ct * 64) = v;
    }
  }
}

// ---------------------------------------------------------------------------
// Fallback (ws too small or N too large): 3 additive passes over out.
// ---------------------------------------------------------------------------
template<int K, int WS, int WOFF, bool GATHER, bool INIT, bool FINAL>
__global__ __launch_bounds__(256) void pass_kernel(
    const float* __restrict__ src, const int* __restrict__ gidx,
    const float* __restrict__ W, const float* __restrict__ beff,
    float* __restrict__ out, int E)
{
  int e = blockIdx.x * 256 + threadIdx.x;
  if (e >= E) return;
  long rowi = GATHER ? (long)gidx[e] : (long)e;

  float4 rv[K / 4];
  const float4* sp = (const float4*)(src + rowi * K);
  #pragma unroll
  for (int c = 0; c < K / 4; ++c) rv[c] = sp[c];

  float* orow = out + (long)e * D;
  for (int ob = 0; ob < D; ob += 4) {
    float acc[4];
    if (INIT) {
      float4 b4 = *(const float4*)&beff[ob];
      acc[0] = b4.x; acc[1] = b4.y; acc[2] = b4.z; acc[3] = b4.w;
    } else {
      float4 p4 = *(const float4*)&orow[ob];
      acc[0] = p4.x; acc[1] = p4.y; acc[2] = p4.z; acc[3] = p4.w;
    }
    #pragma unroll
    for (int k = 0; k < 4; ++k) {
      const float4* wv = (const float4*)&W[(long)(ob + k) * WS + WOFF];
      float a = acc[k];
      #pragma unroll
      for (int c = 0; c < K / 4; ++c) {
        float4 w4 = wv[c]; float4 r4 = rv[c];
        a = fmaf(w4.x, r4.x, a); a = fmaf(w4.y, r4.y, a);
        a = fmaf(w4.z, r4.z, a); a = fmaf(w4.w, r4.w, a);
      }
      acc[k] = a;
    }
    float4 o4;
    o4.x = FINAL ? ssp_f(acc[0]) : acc[0];
    o4.y = FINAL ? ssp_f(acc[1]) : acc[1];
    o4.z = FINAL ? ssp_f(acc[2]) : acc[2];
    o4.w = FINAL ? ssp_f(acc[3]) : acc[3];
    *(float4*)&orow[ob] = o4;
  }
}

// ---------------------------------------------------------------------------
extern "C" void kernel_launch(void* const* d_in, const int* in_sizes, int n_in,
                              void* d_out, int out_size, void* d_ws, size_t ws_size,
                              hipStream_t stream)
{
  const float* vi    = (const float*)d_in[0];
  const float* rbf   = (const float*)d_in[1];
  const float* W_rbf = (const float*)d_in[2];
  const float* b_rbf = (const float*)d_in[3];
  const float* W_cat = (const float*)d_in[4];
  const float* b_cat = (const float*)d_in[5];
  const int*   eidx  = (const int*)d_in[6];

  const int N = in_sizes[0] / D;
  const int E = in_sizes[6] / 2;
  float* out = (float*)d_out;

  float* ws   = (float*)d_ws;
  float* weff = ws;                               // 8192 floats
  float* beff = ws + D * DR;                      // 128 floats (ends 8320)
  unsigned short* weffh = (unsigned short*)(ws + 8448);  // 8192 ushort
  float* Pj   = ws + 8448 + 4096;                 // N*128 floats
  float* Pi   = Pj + (size_t)N * D;
  size_t need = (8448 + 4096 + 2 * (size_t)N * D) * sizeof(float);

  const int use_fast = (ws_size >= need && E >= 1 && N < 4000000);
  stage0_kernel<<<32, 256, 0, stream>>>(W_rbf, b_rbf, W_cat, b_cat,
                                        weff, weffh, beff, use_fast);

  if (use_fast) {
    stage1_kernel<<<(N + NB - 1) / NB, 256, 0, stream>>>(vi, W_cat, Pj, Pi, N);
    int fblocks = (int)(((long)E + 63) / 64);   // 4 waves x 16 edges per block
    edge_mfma_kernel<<<fblocks, 256, 0, stream>>>(rbf, eidx, weffh, beff,
                                                  Pj, Pi, out, E);
  } else {
    int eblocks = (E + 255) / 256;
    pass_kernel<DR, DR, 0,  false, true,  false><<<eblocks, 256, 0, stream>>>(rbf, nullptr,  weff,  beff, out, E);
    pass_kernel<D, 384, 128, true, false, false><<<eblocks, 256, 0, stream>>>(vi,  eidx + E, W_cat, beff, out, E);
    pass_kernel<D, 384, 256, true, false, true ><<<eblocks, 256, 0, stream>>>(vi,  eidx,     W_cat, beff, out, E);
  }
}

// Round 16
// 287.296 us; speedup vs baseline: 1.2104x; 1.2104x over previous
//
#include <hip/hip_runtime.h>
#include <cmath>

#define D  128   // D_EDGE
#define DR 64    // D_RBF
#define NB 32    // nodes per block in stage1

typedef float fx4    __attribute__((ext_vector_type(4)));
typedef float f32x16 __attribute__((ext_vector_type(16)));
typedef short short8v __attribute__((ext_vector_type(8)));

__device__ __forceinline__ float ssp_f(float x) {
  // softplus(x) - log(2), numerically stable
  float m = fmaxf(x, 0.0f);
  float t = __expf(-fabsf(x));
  return m + __logf(1.0f + t) - 0.69314718055994531f;
}

__device__ __forceinline__ short f2bf(float f) {   // fp32 -> bf16 (RNE)
  unsigned u = __float_as_uint(f);
  u = (u + 0x7FFFu + ((u >> 16) & 1u)) >> 16;
  return (short)u;
}

__device__ __forceinline__ float bf2f(unsigned short h) {  // bf16 -> fp32
  return __uint_as_float(((unsigned)h) << 16);
}

// ---------------------------------------------------------------------------
// stage0: W_eff = W_cat[:, :128] @ W_rbf (128x64), b_eff; also bf16 copy.
// ---------------------------------------------------------------------------
__global__ __launch_bounds__(256) void stage0_kernel(
    const float* __restrict__ W_rbf, const float* __restrict__ b_rbf,
    const float* __restrict__ W_cat, const float* __restrict__ b_cat,
    float* __restrict__ weff, unsigned short* __restrict__ weffh,
    float* __restrict__ beff, int write_bf16)
{
  int gid = blockIdx.x * 256 + threadIdx.x;
  if (gid < D * DR) {
    int o = gid >> 6;
    int r = gid & 63;
    float acc = 0.0f;
    #pragma unroll 8
    for (int d = 0; d < D; ++d)
      acc = fmaf(W_cat[o * 384 + d], W_rbf[d * DR + r], acc);
    weff[gid] = acc;
    if (write_bf16) weffh[gid] = (unsigned short)f2bf(acc);
  }
  if (gid < D) {
    float acc = b_cat[gid];
    #pragma unroll 8
    for (int d = 0; d < D; ++d)
      acc = fmaf(b_rbf[d], W_cat[gid * 384 + d], acc);
    beff[gid] = acc;
  }
}

// ---------------------------------------------------------------------------
// stage1: PjH[n][o] = bf16(vi[n] . W_cat[o][128:256])
//         PiH[n][o] = bf16(vi[n] . W_cat[o][256:384])
// bf16 tables halve the edge kernel's gather traffic (655 -> 327 MB demand);
// error ~1e-3 vs 4.5e-2 threshold.
// ---------------------------------------------------------------------------
__global__ __launch_bounds__(256) void stage1_kernel(
    const float* __restrict__ vi, const float* __restrict__ W_cat,
    unsigned short* __restrict__ PjH, unsigned short* __restrict__ PiH, int N)
{
  __shared__ float vrow[NB * D];
  int base = blockIdx.x * NB;
  int t = threadIdx.x;
  for (int idx = t * 4; idx < NB * D; idx += 1024) {
    int n = base + (idx >> 7);
    float4 v = make_float4(0.f, 0.f, 0.f, 0.f);
    if (n < N) v = *(const float4*)&vi[(long)n * D + (idx & 127)];
    *(float4*)&vrow[idx] = v;
  }
  __syncthreads();

  int o     = t & 127;
  int which = t >> 7;
  const float* w = W_cat + (long)o * 384 + 128 + which * 128;
  unsigned short* P = which ? PiH : PjH;

  float acc[NB];
  #pragma unroll
  for (int n = 0; n < NB; ++n) acc[n] = 0.0f;

  for (int dd = 0; dd < D; dd += 4) {
    float4 wv = *(const float4*)&w[dd];
    #pragma unroll
    for (int n = 0; n < NB; ++n) {
      float4 v = *(const float4*)&vrow[n * D + dd];
      acc[n] = fmaf(wv.x, v.x, acc[n]);
      acc[n] = fmaf(wv.y, v.y, acc[n]);
      acc[n] = fmaf(wv.z, v.z, acc[n]);
      acc[n] = fmaf(wv.w, v.w, acc[n]);
    }
  }
  #pragma unroll
  for (int n = 0; n < NB; ++n) {
    int nn = base + n;
    if (nn < N) P[(long)nn * D + o] = (unsigned short)f2bf(acc[n]);
  }
}

// ---------------------------------------------------------------------------
// MFMA edge kernel (R11 structure, proven 208us; single change set: bf16
// table gathers + NT on the streaming rbf/out). Wave-autonomous, no LDS,
// no barriers. wave = 64 edges (2 tiles of 32), mfma_f32_32x32x16_bf16.
// C/D layout (HW-verified): col=lane&31, row=(reg&3)+8*(reg>>2)+4*(lane>>5).
// NOTE: never set min-waves launch bounds (R3/R13: forced caps -> 900MB
// scratch spill). Measured occupancy tiers are VGPR 64/128/256; this sits
// ~120 (4 waves/SIMD). R12/R15 showed occupancy is NOT the limiter; the
// memory system caps at ~3.5 TB/s effective for this mix -> cut bytes.
// ---------------------------------------------------------------------------
__global__ __launch_bounds__(256) void edge_mfma_kernel(
    const float* __restrict__ rbf, const int* __restrict__ eidx,
    const unsigned short* __restrict__ weffh, const float* __restrict__ beff,
    const unsigned short* __restrict__ PjH, const unsigned short* __restrict__ PiH,
    float* __restrict__ out, int E)
{
  const int t    = threadIdx.x;
  const int lane = t & 63;
  const int row  = lane & 31;   // A row / B col / C col
  const int half = lane >> 5;   // k-half selector
  const long wid  = (long)blockIdx.x * 4 + (t >> 6);
  const long base = wid * 64;
  if (base >= (long)E) return;

  // B fragments: B[k][n] = weff[n*64+k] (bf16), n=ct*32+row, k=ks*16+8*half+i
  short8v B[4][4];
  #pragma unroll
  for (int ct = 0; ct < 4; ++ct) {
    #pragma unroll
    for (int ks = 0; ks < 4; ++ks)
      B[ct][ks] = *(const short8v*)&weffh[(ct * 32 + row) * DR + ks * 16 + half * 8];
  }
  float bias[4];
  #pragma unroll
  for (int ct = 0; ct < 4; ++ct) bias[ct] = beff[ct * 32 + row];

  #pragma unroll
  for (int tile = 0; tile < 2; ++tile) {
    const long tb = base + (long)tile * 32;
    if (tb >= (long)E) break;
    long er = tb + row; if (er > (long)E - 1) er = (long)E - 1;

    // A fragments straight from global (fp32 -> bf16), NT (read-once stream)
    const float* arow = rbf + er * DR + half * 8;
    short8v A[4];
    #pragma unroll
    for (int ks = 0; ks < 4; ++ks) {
      fx4 lo = __builtin_nontemporal_load((const fx4*)&arow[ks * 16]);
      fx4 hi = __builtin_nontemporal_load((const fx4*)&arow[ks * 16 + 4]);
      short8v a;
      a[0] = f2bf(lo.x); a[1] = f2bf(lo.y); a[2] = f2bf(lo.z); a[3] = f2bf(lo.w);
      a[4] = f2bf(hi.x); a[5] = f2bf(hi.y); a[6] = f2bf(hi.z); a[7] = f2bf(hi.w);
      A[ks] = a;
    }

    // per-lane edge indices for this tile (lane's row = local edge id)
    const int iv = eidx[er];            // edge_index[0] -> h_i -> Pi
    const int jv = eidx[(long)E + er];  // edge_index[1] -> h_j -> Pj

    #pragma unroll
    for (int ct = 0; ct < 4; ++ct) {
      // gathers: 32 bf16 loads in flight (64B/line-pair, L2/L3-resident table)
      float gj[16], gi[16];
      #pragma unroll
      for (int reg = 0; reg < 16; ++reg) {
        const int erl = (reg & 3) + 8 * (reg >> 2) + 4 * half;
        const int j = __shfl(jv, erl);
        const int i = __shfl(iv, erl);
        gj[reg] = bf2f(PjH[(long)j * D + ct * 32 + row]);
        gi[reg] = bf2f(PiH[(long)i * D + ct * 32 + row]);
      }
      __builtin_amdgcn_sched_barrier(0);   // keep gather issue ahead of MFMA

      f32x16 acc = (f32x16)(0.0f);
      acc = __builtin_amdgcn_mfma_f32_32x32x16_bf16(A[0], B[ct][0], acc, 0, 0, 0);
      acc = __builtin_amdgcn_mfma_f32_32x32x16_bf16(A[1], B[ct][1], acc, 0, 0, 0);
      acc = __builtin_amdgcn_mfma_f32_32x32x16_bf16(A[2], B[ct][2], acc, 0, 0, 0);
      acc = __builtin_amdgcn_mfma_f32_32x32x16_bf16(A[3], B[ct][3], acc, 0, 0, 0);

      #pragma unroll
      for (int reg = 0; reg < 16; ++reg) {
        const int erl = (reg & 3) + 8 * (reg >> 2) + 4 * half;
        const long ge = tb + erl;
        const float v = ssp_f(acc[reg] + gj[reg] + gi[reg] + bias[ct]);
        if (ge < (long)E)
          __builtin_nontemporal_store(v, &out[ge * D + ct * 32 + row]);
      }
    }
  }
}

// ---------------------------------------------------------------------------
// Fallback (only if d_ws is too small): 3 additive passes over out, fp32.
// ---------------------------------------------------------------------------
template<int K, int WS, int WOFF, bool GATHER, bool INIT, bool FINAL>
__global__ __launch_bounds__(256) void pass_kernel(
    const float* __restrict__ src, const int* __restrict__ gidx,
    const float* __restrict__ W, const float* __restrict__ beff,
    float* __restrict__ out, int E)
{
  int e = blockIdx.x * 256 + threadIdx.x;
  if (e >= E) return;
  long rowi = GATHER ? (long)gidx[e] : (long)e;

  float4 rv[K / 4];
  const float4* sp = (const float4*)(src + rowi * K);
  #pragma unroll
  for (int c = 0; c < K / 4; ++c) rv[c] = sp[c];

  float* orow = out + (long)e * D;
  for (int ob = 0; ob < D; ob += 4) {
    float acc[4];
    if (INIT) {
      float4 b4 = *(const float4*)&beff[ob];
      acc[0] = b4.x; acc[1] = b4.y; acc[2] = b4.z; acc[3] = b4.w;
    } else {
      float4 p4 = *(const float4*)&orow[ob];
      acc[0] = p4.x; acc[1] = p4.y; acc[2] = p4.z; acc[3] = p4.w;
    }
    #pragma unroll
    for (int k = 0; k < 4; ++k) {
      const float4* wv = (const float4*)&W[(long)(ob + k) * WS + WOFF];
      float a = acc[k];
      #pragma unroll
      for (int c = 0; c < K / 4; ++c) {
        float4 w4 = wv[c]; float4 r4 = rv[c];
        a = fmaf(w4.x, r4.x, a); a = fmaf(w4.y, r4.y, a);
        a = fmaf(w4.z, r4.z, a); a = fmaf(w4.w, r4.w, a);
      }
      acc[k] = a;
    }
    float4 o4;
    o4.x = FINAL ? ssp_f(acc[0]) : acc[0];
    o4.y = FINAL ? ssp_f(acc[1]) : acc[1];
    o4.z = FINAL ? ssp_f(acc[2]) : acc[2];
    o4.w = FINAL ? ssp_f(acc[3]) : acc[3];
    *(float4*)&orow[ob] = o4;
  }
}

// ---------------------------------------------------------------------------
extern "C" void kernel_launch(void* const* d_in, const int* in_sizes, int n_in,
                              void* d_out, int out_size, void* d_ws, size_t ws_size,
                              hipStream_t stream)
{
  const float* vi    = (const float*)d_in[0];
  const float* rbf   = (const float*)d_in[1];
  const float* W_rbf = (const float*)d_in[2];
  const float* b_rbf = (const float*)d_in[3];
  const float* W_cat = (const float*)d_in[4];
  const float* b_cat = (const float*)d_in[5];
  const int*   eidx  = (const int*)d_in[6];

  const int N = in_sizes[0] / D;
  const int E = in_sizes[6] / 2;
  float* out = (float*)d_out;

  float* ws   = (float*)d_ws;
  float* weff = ws;                               // 8192 floats
  float* beff = ws + D * DR;                      // 128 floats (ends 8320)
  unsigned short* weffh = (unsigned short*)(ws + 8448);   // 8192 ushort
  unsigned short* PjH = (unsigned short*)(ws + 8448 + 4096);  // N*128 ushort
  unsigned short* PiH = PjH + (size_t)N * D;
  size_t need = (8448 + 4096 + (size_t)N * 128) * sizeof(float); // incl both tables

  const int use_fast = (ws_size >= need && E >= 1);
  stage0_kernel<<<32, 256, 0, stream>>>(W_rbf, b_rbf, W_cat, b_cat,
                                        weff, weffh, beff, use_fast);

  if (use_fast) {
    stage1_kernel<<<(N + NB - 1) / NB, 256, 0, stream>>>(vi, W_cat, PjH, PiH, N);
    long waves = ((long)E + 63) / 64;
    int fblocks = (int)((waves + 3) / 4);
    edge_mfma_kernel<<<fblocks, 256, 0, stream>>>(rbf, eidx, weffh, beff,
                                                  PjH, PiH, out, E);
  } else {
    int eblocks = (E + 255) / 256;
    pass_kernel<DR, DR, 0,  false, true,  false><<<eblocks, 256, 0, stream>>>(rbf, nullptr,  weff,  beff, out, E);
    pass_kernel<D, 384, 128, true, false, false><<<eblocks, 256, 0, stream>>>(vi,  eidx + E, W_cat, beff, out, E);
    pass_kernel<D, 384, 256, true, false, true ><<<eblocks, 256, 0, stream>>>(vi,  eidx,     W_cat, beff, out, E);
  }
}